// Round 2
// baseline (533.217 us; speedup 1.0000x reference)
//
#include <hip/hip_runtime.h>

// Problem dims (fixed by reference)
#define Bdim 16
#define Sdim 128
#define Mdim 128
#define Ddim 256   // emb dim
#define Hdim 256   // hidden dim
#define NPB 2      // nodes per block
#define NT  512    // threads per block (8 waves)

// Block = 512 threads = 8 waves, handles 2 nodes (4 waves per node).
// Grid = 1024 blocks -> 4 blocks/CU co-resident (VGPR<=64, LDS 20.5KB) ->
// 32 waves/CU, double the previous occupancy; phase-1 is latency-bound so
// resident-wave count is the lever.
// Phase 1: wave w covers the contiguous 32-row chunk [(w&3)*32, (w&3)*32+32)
//          of node w>>2; 64 lanes * float4 = one full 256-col row per iter,
//          so __any() gives the row-validity bit exactly. 4-row batches ->
//          8 float4 loads in flight per thread, imm offsets 0/1024/2048/3072.
// Phase 2: LDS combine 4 waves -> hidden[2][512].
// Phase 3: fused GEMM row: W_map read ONCE per block for 2 nodes, both
//          halves read the same W[k][t] concurrently (L1 dedup),
//          + bias + leaky_relu.
__global__ __launch_bounds__(NT, 8) void gcn_fused3(
    const float* __restrict__ src,
    const float* __restrict__ neigh,
    const float* __restrict__ Wmap,   // [2D, H] row-major
    const float* __restrict__ bmap,   // [H]
    float* __restrict__ out)          // [B*S, H]
{
    const int tid   = threadIdx.x;
    const int wave  = tid >> 6;       // 0..7
    const int lane  = tid & 63;
    const int lnode = wave >> 2;      // 0..1 local node
    const int mph   = wave & 3;       // 32-row chunk index within node

    const size_t base4 = (size_t)(blockIdx.x * NPB + lnode) * (Mdim * Ddim / 4);
    const float4* __restrict__ src4 = (const float4*)src + base4 + (size_t)(mph * 32) * (Ddim / 4) + lane;
    const float4* __restrict__ ngh4 = (const float4*)neigh + base4 + (size_t)(mph * 32) * (Ddim / 4) + lane;

    float4 sacc = make_float4(0.f, 0.f, 0.f, 0.f);
    float4 nacc = make_float4(0.f, 0.f, 0.f, 0.f);
    int cnt = 0;

    // wave covers 32 consecutive rows; batch 4 rows -> 8 loads in flight
    for (int i0 = 0; i0 < 32; i0 += 4) {
        float4 sv[4], nv[4];
        #pragma unroll
        for (int j = 0; j < 4; ++j) {
            const int idx = (i0 + j) * (Ddim / 4);
            sv[j] = src4[idx];
            nv[j] = ngh4[idx];
        }
        #pragma unroll
        for (int j = 0; j < 4; ++j) {
            sacc.x += sv[j].x; sacc.y += sv[j].y; sacc.z += sv[j].z; sacc.w += sv[j].w;
            nacc.x += nv[j].x; nacc.y += nv[j].y; nacc.z += nv[j].z; nacc.w += nv[j].w;
            int nz = (nv[j].x != 0.f) | (nv[j].y != 0.f) | (nv[j].z != 0.f) | (nv[j].w != 0.f);
            if (__any(nz)) cnt++;   // wave-wide OR over the row's 256 columns
        }
    }

    __shared__ float s_s[8][Ddim];        // 8 KiB per-wave partial src sums
    __shared__ float s_n[8][Ddim];        // 8 KiB per-wave partial neigh sums
    __shared__ int   s_cnt[8];
    __shared__ float hid[NPB][2 * Ddim];  // 4 KiB GEMM input rows

    *(float4*)&s_s[wave][lane * 4] = sacc;
    *(float4*)&s_n[wave][lane * 4] = nacc;
    if (lane == 0) s_cnt[wave] = cnt;
    __syncthreads();

    // combine 4 waves -> hidden rows. 512 threads cover 2 nodes x 512 cols:
    // threads 0..255 build the src-sum half, 256..511 the neigh-mean half.
    {
        const int t    = tid & (Ddim - 1);
        const int half = tid >> 8;
        #pragma unroll
        for (int n = 0; n < NPB; ++n) {
            if (half == 0) {
                hid[n][t] = (s_s[4 * n][t] + s_s[4 * n + 1][t])
                          + (s_s[4 * n + 2][t] + s_s[4 * n + 3][t]);
            } else {
                const float num = (float)(s_cnt[4 * n] + s_cnt[4 * n + 1]
                                        + s_cnt[4 * n + 2] + s_cnt[4 * n + 3]);
                const float inv = 1.0f / fmaxf(num, 1.0f);
                hid[n][Ddim + t] = ((s_n[4 * n][t] + s_n[4 * n + 1][t])
                                  + (s_n[4 * n + 2][t] + s_n[4 * n + 3][t])) * inv;
            }
        }
    }
    __syncthreads();

    // GEMM: thread -> (col t, node tid>>8). Both halves load the same W[k][t]
    // at the same time -> L1 dedup; W read once per block from L2.
    const int t = tid & (Ddim - 1);
    const int n = tid >> 8;
    float acc0 = bmap[t];
    float acc1 = 0.f;
    const float4* __restrict__ h = (const float4*)hid[n];

    #pragma unroll 4
    for (int k4 = 0; k4 < (2 * Ddim) / 4; ++k4) {
        const float4 ha = h[k4];            // ds_read_b128, wave-broadcast
        const int k = k4 * 4;
        const float w0 = Wmap[(size_t)(k + 0) * Hdim + t];
        const float w1 = Wmap[(size_t)(k + 1) * Hdim + t];
        const float w2 = Wmap[(size_t)(k + 2) * Hdim + t];
        const float w3 = Wmap[(size_t)(k + 3) * Hdim + t];
        acc0 = fmaf(ha.x, w0, acc0);
        acc1 = fmaf(ha.y, w1, acc1);
        acc0 = fmaf(ha.z, w2, acc0);
        acc1 = fmaf(ha.w, w3, acc1);
    }

    const float acc = acc0 + acc1;
    const float r = acc > 0.f ? acc : 0.01f * acc;
    out[(size_t)(blockIdx.x * NPB + n) * Hdim + t] = r;
}

extern "C" void kernel_launch(void* const* d_in, const int* in_sizes, int n_in,
                              void* d_out, int out_size, void* d_ws, size_t ws_size,
                              hipStream_t stream) {
    const float* src   = (const float*)d_in[0];
    const float* neigh = (const float*)d_in[1];
    const float* Wmap  = (const float*)d_in[2];
    const float* bmap  = (const float*)d_in[3];
    float* out = (float*)d_out;

    dim3 grid((Bdim * Sdim) / NPB);   // 1024 blocks, 2 nodes each
    dim3 block(NT);
    gcn_fused3<<<grid, block, 0, stream>>>(src, neigh, Wmap, bmap, out);
}

// Round 3
// 518.965 us; speedup vs baseline: 1.0275x; 1.0275x over previous
//
#include <hip/hip_runtime.h>

// Problem dims (fixed by reference)
#define Bdim 16
#define Sdim 128
#define Mdim 128
#define Ddim 256   // emb dim
#define Hdim 256   // hidden dim
#define NPB 2      // nodes per block
#define NT  512    // threads per block (8 waves)

// Block = 512 threads = 8 waves, 2 nodes (4 waves/node).
// launch_bounds(512,4): VGPR budget 128 -> NO spilling (round-2 lesson:
// (512,8) forced VGPR=32, spilled 22MB to scratch, de-pipelined loads).
// MLP is the lever: 16 float4 loads in flight per thread (8 rows x 2 arrays,
// 64 VGPRs of data). 16 waves/CU x 16 outstanding 1KB wave-loads = 2x the
// in-flight bytes of round 0 at equal wave count -> target ~10 B/cyc/CU
// (the m13 copy-kernel rate) vs the ~5 measured in rounds 0/2.
// Grid 1024 = 2 rounds of 2 resident blocks/CU -> GEMM tail of round-1
// blocks overlaps streaming of round-2 blocks.
__global__ __launch_bounds__(NT, 4) void gcn_fused4(
    const float* __restrict__ src,
    const float* __restrict__ neigh,
    const float* __restrict__ Wmap,   // [2D, H] row-major
    const float* __restrict__ bmap,   // [H]
    float* __restrict__ out)          // [B*S, H]
{
    const int tid   = threadIdx.x;
    const int wave  = tid >> 6;       // 0..7
    const int lane  = tid & 63;
    const int lnode = wave >> 2;      // 0..1 local node
    const int mph   = wave & 3;       // 32-row chunk index within node

    const size_t base4 = (size_t)(blockIdx.x * NPB + lnode) * (Mdim * Ddim / 4);
    const float4* __restrict__ src4 = (const float4*)src + base4 + (size_t)(mph * 32) * (Ddim / 4) + lane;
    const float4* __restrict__ ngh4 = (const float4*)neigh + base4 + (size_t)(mph * 32) * (Ddim / 4) + lane;

    float4 sacc = make_float4(0.f, 0.f, 0.f, 0.f);
    float4 nacc = make_float4(0.f, 0.f, 0.f, 0.f);
    int cnt = 0;

    // wave covers 32 consecutive rows; batch 8 rows of BOTH arrays ->
    // 16 float4 loads in flight per thread (imm offsets 0..7168B).
    for (int i0 = 0; i0 < 32; i0 += 8) {
        float4 sv[8], nv[8];
        #pragma unroll
        for (int j = 0; j < 8; ++j) {
            const int idx = (i0 + j) * (Ddim / 4);
            sv[j] = src4[idx];
            nv[j] = ngh4[idx];
        }
        #pragma unroll
        for (int j = 0; j < 8; ++j) {
            sacc.x += sv[j].x; sacc.y += sv[j].y; sacc.z += sv[j].z; sacc.w += sv[j].w;
            nacc.x += nv[j].x; nacc.y += nv[j].y; nacc.z += nv[j].z; nacc.w += nv[j].w;
            int nz = (nv[j].x != 0.f) | (nv[j].y != 0.f) | (nv[j].z != 0.f) | (nv[j].w != 0.f);
            if (__any(nz)) cnt++;   // wave-wide OR over the row's 256 columns
        }
    }

    __shared__ float s_s[8][Ddim];        // 8 KiB per-wave partial src sums
    __shared__ float s_n[8][Ddim];        // 8 KiB per-wave partial neigh sums
    __shared__ int   s_cnt[8];
    __shared__ float hid[NPB][2 * Ddim];  // 4 KiB GEMM input rows

    *(float4*)&s_s[wave][lane * 4] = sacc;
    *(float4*)&s_n[wave][lane * 4] = nacc;
    if (lane == 0) s_cnt[wave] = cnt;
    __syncthreads();

    // combine 4 waves -> hidden rows. 512 threads cover 2 nodes x 512 cols:
    // threads 0..255 build the src-sum half, 256..511 the neigh-mean half.
    {
        const int t    = tid & (Ddim - 1);
        const int half = tid >> 8;
        #pragma unroll
        for (int n = 0; n < NPB; ++n) {
            if (half == 0) {
                hid[n][t] = (s_s[4 * n][t] + s_s[4 * n + 1][t])
                          + (s_s[4 * n + 2][t] + s_s[4 * n + 3][t]);
            } else {
                const float num = (float)(s_cnt[4 * n] + s_cnt[4 * n + 1]
                                        + s_cnt[4 * n + 2] + s_cnt[4 * n + 3]);
                const float inv = 1.0f / fmaxf(num, 1.0f);
                hid[n][Ddim + t] = ((s_n[4 * n][t] + s_n[4 * n + 1][t])
                                  + (s_n[4 * n + 2][t] + s_n[4 * n + 3][t])) * inv;
            }
        }
    }
    __syncthreads();

    // GEMM: thread -> (col t, node tid>>8). Both halves load the same W[k][t]
    // at the same time -> L1 dedup; W read once per block from L2.
    const int t = tid & (Ddim - 1);
    const int n = tid >> 8;
    float acc0 = bmap[t];
    float acc1 = 0.f;
    const float4* __restrict__ h = (const float4*)hid[n];

    #pragma unroll 4
    for (int k4 = 0; k4 < (2 * Ddim) / 4; ++k4) {
        const float4 ha = h[k4];            // ds_read_b128, wave-broadcast
        const int k = k4 * 4;
        const float w0 = Wmap[(size_t)(k + 0) * Hdim + t];
        const float w1 = Wmap[(size_t)(k + 1) * Hdim + t];
        const float w2 = Wmap[(size_t)(k + 2) * Hdim + t];
        const float w3 = Wmap[(size_t)(k + 3) * Hdim + t];
        acc0 = fmaf(ha.x, w0, acc0);
        acc1 = fmaf(ha.y, w1, acc1);
        acc0 = fmaf(ha.z, w2, acc0);
        acc1 = fmaf(ha.w, w3, acc1);
    }

    const float acc = acc0 + acc1;
    const float r = acc > 0.f ? acc : 0.01f * acc;
    out[(size_t)(blockIdx.x * NPB + n) * Hdim + t] = r;
}

extern "C" void kernel_launch(void* const* d_in, const int* in_sizes, int n_in,
                              void* d_out, int out_size, void* d_ws, size_t ws_size,
                              hipStream_t stream) {
    const float* src   = (const float*)d_in[0];
    const float* neigh = (const float*)d_in[1];
    const float* Wmap  = (const float*)d_in[2];
    const float* bmap  = (const float*)d_in[3];
    float* out = (float*)d_out;

    dim3 grid((Bdim * Sdim) / NPB);   // 1024 blocks, 2 nodes each
    dim3 block(NT);
    gcn_fused4<<<grid, block, 0, stream>>>(src, neigh, Wmap, bmap, out);
}